// Round 2
// baseline (199.524 us; speedup 1.0000x reference)
//
#include <hip/hip_runtime.h>

#define BB 4
#define NN 2048
#define INF 256
#define HH 8
#define DD 32
#define LOG2E 1.4426950408889634f

typedef __attribute__((ext_vector_type(8))) short short8;
typedef __attribute__((ext_vector_type(4))) float f32x4;

__device__ __forceinline__ unsigned short bf16_rne(float v) {
    unsigned b = __float_as_uint(v);
    return (unsigned short)((b + 0x7fffu + ((b >> 16) & 1u)) >> 16);
}
__device__ __forceinline__ unsigned short bf16_rhu(float v) {
    return (unsigned short)((__float_as_uint(v) + 0x8000u) >> 16);
}

// ekadj: low-LDS fusion. bid%5==0 -> ek (512 blocks, 33KB LDS, 4 blk/CU);
// else -> adjbits (2048 blocks, coalesced ballot compression, 1 row/wave).
__global__ __launch_bounds__(256) void ekadj_kernel(
    const float* __restrict__ x, const int* __restrict__ adj,
    const float* __restrict__ W, const float* __restrict__ a,
    float* __restrict__ esrc, unsigned* __restrict__ ejP,
    unsigned* __restrict__ bitsG)
{
    __shared__ __align__(16) float smem[2 * 16 * 260];
    const int bid = blockIdx.x, t = threadIdx.x;
    const int bq = bid / 5, br = bid % 5;

    if (br != 0) {                         // ---- adjbits ----
        const int id = bq * 4 + (br - 1);  // 0..2047
        const int wv = t >> 6, l = t & 63;
        const int row = id * 4 + wv;       // global (b*N + i) row
        const int* ap = adj + (size_t)row * NN;
        #pragma unroll 8
        for (int c = 0; c < 32; ++c) {
            int val = ap[c * 64 + l];      // 256B contiguous per wave-instr
            unsigned long long m = __ballot(val != 0);
            if (l == 0) bitsG[(size_t)row * 64 + c * 2]     = (unsigned)m;
            if (l == 1) bitsG[(size_t)row * 64 + c * 2 + 1] = (unsigned)(m >> 32);
        }
        return;
    }

    // ---- ek: exact fp32 e-dots; we (W·a) inline (a wave-uniform -> s_loads) ----
    float* xs    = smem;                   // [16][260]
    float* weld2 = smem + 16 * 260;        // [c=f>>4][k*16+fi]
    const int id = bq;
    const int tile = id & 127, b = id >> 7;
    const int n0 = tile * 16;

    #pragma unroll
    for (int p = 0; p < 4; ++p) {
        int flat = p * 1024 + t * 4;
        int row = flat >> 8, col = flat & 255;
        f32x4 g = *(const f32x4*)&x[((size_t)(b * NN + n0 + row)) * INF + col];
        *(f32x4*)&xs[row * 260 + col] = g;
    }
    {
        const int f = t;
        #pragma unroll
        for (int h = 0; h < 8; ++h) {
            const float* wr = W + ((size_t)(h * INF + f)) * DD;
            float s0 = 0.f, s1 = 0.f;
            #pragma unroll
            for (int d = 0; d < DD; ++d) {
                float wv = wr[d];
                s0 += wv * a[h * 2 * DD + d];
                s1 += wv * a[h * 2 * DD + DD + d];
            }
            weld2[(f >> 4) * 260 + h * 16 + (f & 15)]       = s0 * LOG2E;
            weld2[(f >> 4) * 260 + (h + 8) * 16 + (f & 15)] = s1 * LOG2E;
        }
    }
    __syncthreads();

    const int row = t >> 4, cc = t & 15;
    f32x4 xv[4];
    #pragma unroll
    for (int i = 0; i < 4; ++i)
        xv[i] = *(const f32x4*)&xs[row * 260 + cc * 16 + i * 4];

    float keep = 0.f;
    #pragma unroll
    for (int k = 0; k < 16; ++k) {
        float s = 0.f;
        #pragma unroll
        for (int i = 0; i < 4; ++i) {
            f32x4 w4 = *(const f32x4*)&weld2[cc * 260 + k * 16 + i * 4];
            s += xv[i][0]*w4[0] + xv[i][1]*w4[1] + xv[i][2]*w4[2] + xv[i][3]*w4[3];
        }
        s += __shfl_xor(s, 1, 64);
        s += __shfl_xor(s, 2, 64);
        s += __shfl_xor(s, 4, 64);
        s += __shfl_xor(s, 8, 64);
        keep = (cc == k) ? s : keep;
    }
    const int n = n0 + row;
    if (cc < 8) {
        esrc[(b * 8 + cc) * NN + n] = keep;
    } else {
        float Ej  = __builtin_amdgcn_exp2f(keep);
        float Ej5 = __builtin_amdgcn_exp2f(0.2f * keep);
        ejP[(b * 8 + (cc - 8)) * NN + n] =
            ((unsigned)bf16_rne(Ej) << 16) | (unsigned)bf16_rne(Ej5);
    }
}

// whk: 64 rows x 64 cols (2 heads) x K=256 MFMA GEMM; W->wb bf16 transpose inline.
// grid 512 x 256.
__global__ __launch_bounds__(256) void whk_kernel(
    const float* __restrict__ x, const float* __restrict__ W,
    unsigned short* __restrict__ whT2)
{
    __shared__ __align__(16) unsigned short xb[64 * 264];
    __shared__ __align__(16) unsigned short wb[64 * 264];
    const int t = threadIdx.x;
    const int hp = blockIdx.x & 3, tl = (blockIdx.x >> 2) & 31, b = blockIdx.x >> 7;
    const int n0 = tl * 64;

    #pragma unroll
    for (int p = 0; p < 16; ++p) {                   // x tile -> bf16 LDS
        int flat = p * 1024 + t * 4;
        int row = flat >> 8, col = flat & 255;
        f32x4 g = *(const f32x4*)&x[((size_t)(b * NN + n0 + row)) * INF + col];
        unsigned a0 = __float_as_uint(g[0]) + 0x8000u;
        unsigned a1 = __float_as_uint(g[1]) + 0x8000u;
        unsigned a2 = __float_as_uint(g[2]) + 0x8000u;
        unsigned a3 = __float_as_uint(g[3]) + 0x8000u;
        uint2 pk;
        pk.x = __builtin_amdgcn_perm(a1, a0, 0x07060302u);
        pk.y = __builtin_amdgcn_perm(a3, a2, 0x07060302u);
        *(uint2*)&xb[row * 264 + col] = pk;
    }
    #pragma unroll
    for (int p = 0; p < 16; ++p) {                   // W slice (fp32) -> wb^T bf16
        int flat = p * 1024 + t * 4;                 // 16384 floats = 2 heads
        int h2 = flat >> 13, rem = flat & 8191;
        int f = rem >> 5, d0 = rem & 31;
        f32x4 g = *(const f32x4*)&W[(((size_t)(hp * 2 + h2)) * INF + f) * DD + d0];
        #pragma unroll
        for (int i = 0; i < 4; ++i)
            wb[(h2 * 32 + d0 + i) * 264 + f] = bf16_rhu(g[i]);
    }
    __syncthreads();

    const int w = t >> 6, l = t & 63;
    const int ml = l & 15, q = l >> 4;
    f32x4 acc[4] = {};
    const unsigned short* apx = &xb[(w * 16 + ml) * 264 + q * 8];
    #pragma unroll
    for (int k0 = 0; k0 < INF; k0 += 32) {
        short8 A = *(const short8*)&apx[k0];
        #pragma unroll
        for (int c16 = 0; c16 < 4; ++c16) {
            short8 Bf = *(const short8*)&wb[(c16 * 16 + ml) * 264 + q * 8 + k0];
            acc[c16] = __builtin_amdgcn_mfma_f32_16x16x32_bf16(A, Bf, acc[c16], 0, 0, 0);
        }
    }
    __syncthreads();
    unsigned short* ldsC = xb;                       // [64 col][72 row]
    #pragma unroll
    for (int c16 = 0; c16 < 4; ++c16)
        #pragma unroll
        for (int r = 0; r < 4; ++r) {
            int col = c16 * 16 + ml;
            int rt  = w * 16 + q * 4 + r;
            ldsC[col * 72 + rt] = bf16_rhu(acc[c16][r]);
        }
    __syncthreads();
    #pragma unroll
    for (int p = 0; p < 2; ++p) {
        int g = p * 256 + t;
        int d = g & 31, jo = (g >> 5) & 7, h2 = g >> 8;
        short8 vv = *(const short8*)&ldsC[(h2 * 32 + d) * 72 + jo * 8];
        int bh = b * 8 + hp * 2 + h2;
        *(short8*)&whT2[(((size_t)bh * 256 + tl * 8 + jo) * 32 + d) * 8] = vv;
    }
}

// attn: 256 blocks x 1024 thr; 16 waves = 8 heads x 2 j-halves, R=2 (32 i-rows).
// No per-chunk barriers, no staging: adj mask read directly from bitsG.
// p' = max(Ej, Fj*Gi), Gi = 2^(-0.8 ei): per-row scale cancels in softmax.
__global__ __launch_bounds__(1024, 4) void attn_kernel(
    const unsigned short* __restrict__ whT2, const float* __restrict__ esrc,
    const unsigned* __restrict__ ejP, const unsigned* __restrict__ bitsG,
    float* __restrict__ out)
{
    __shared__ __align__(16) float cmb[8][64][25];   // stride 25: no bank alias
    const int t = threadIdx.x, v = t >> 6, l = t & 63;
    const int h = v & 7, js = v >> 3;
    const int ml = l & 15, q = l >> 4;
    const int it = blockIdx.x & 63, b = blockIdx.x >> 6;
    const int i0 = it * 32;
    const int bh = b * HH + h;

    const float ei0 = esrc[bh * NN + i0 + ml];
    const float ei1 = esrc[bh * NN + i0 + 16 + ml];
    const float Gi0 = __builtin_amdgcn_exp2f(-0.8f * ei0);
    const float Gi1 = __builtin_amdgcn_exp2f(-0.8f * ei1);

    const unsigned* epP = ejP + bh * NN + js * 1024;
    const unsigned short* whb = whT2 + ((size_t)bh * 256 + js * 128) * 256;
    const unsigned* mb0 = bitsG + ((size_t)(b * NN + i0 + ml)) * 64 + js * 32;
    const unsigned* mb1 = mb0 + (size_t)16 * 64;

    const short8 ones = {0x3F80, 0x3F80, 0x3F80, 0x3F80,
                         0x3F80, 0x3F80, 0x3F80, 0x3F80};
    f32x4 acc00 = {}, acc01 = {}, acc10 = {}, acc11 = {}, accD0 = {}, accD1 = {};

    for (int c = 0; c < 8; ++c) {
        unsigned w0a[4], w1a[4];
        *(uint4*)w0a = *(const uint4*)&mb0[c * 4];
        *(uint4*)w1a = *(const uint4*)&mb1[c * 4];
        const unsigned* epc = epP + c * 128;
        #pragma unroll
        for (int k = 0; k < 4; ++k) {
            const int jb = k * 32 + q * 8;
            uint4 epA = *(const uint4*)&epc[jb];
            uint4 epB = *(const uint4*)&epc[jb + 4];
            const unsigned short* wp = whb + (size_t)(c * 16 + k * 4 + q) * 256;
            short8 B0 = *(const short8*)&wp[ml * 8];
            short8 B1 = *(const short8*)&wp[(16 + ml) * 8];
            unsigned st0 = w0a[k] >> (q * 8);
            unsigned st1 = w1a[k] >> (q * 8);
            union { unsigned u[4]; short8 s; } f0, f1;
            const unsigned* ea = &epA.x;
            const unsigned* eb = &epB.x;
            #pragma unroll
            for (int pp = 0; pp < 4; ++pp) {
                unsigned pkA = (pp < 2) ? ea[2 * pp]     : eb[2 * pp - 4];
                unsigned pkB = (pp < 2) ? ea[2 * pp + 1] : eb[2 * pp - 3];
                float EjA = __uint_as_float(pkA & 0xffff0000u);
                float FjA = __uint_as_float(pkA << 16);
                float EjB = __uint_as_float(pkB & 0xffff0000u);
                float FjB = __uint_as_float(pkB << 16);
                unsigned mA0 = (unsigned)__builtin_amdgcn_sbfe(st0, 2 * pp, 1);
                unsigned mB0 = (unsigned)__builtin_amdgcn_sbfe(st0, 2 * pp + 1, 1);
                unsigned mA1 = (unsigned)__builtin_amdgcn_sbfe(st1, 2 * pp, 1);
                unsigned mB1 = (unsigned)__builtin_amdgcn_sbfe(st1, 2 * pp + 1, 1);
                float pA0 = fmaxf(EjA, FjA * Gi0);
                float pB0 = fmaxf(EjB, FjB * Gi0);
                float pA1 = fmaxf(EjA, FjA * Gi1);
                float pB1 = fmaxf(EjB, FjB * Gi1);
                f0.u[pp] = __builtin_amdgcn_perm(__float_as_uint(pB0) & mB0,
                                                 __float_as_uint(pA0) & mA0,
                                                 0x07060302u);
                f1.u[pp] = __builtin_amdgcn_perm(__float_as_uint(pB1) & mB1,
                                                 __float_as_uint(pA1) & mA1,
                                                 0x07060302u);
            }
            acc00 = __builtin_amdgcn_mfma_f32_16x16x32_bf16(f0.s, B0, acc00, 0, 0, 0);
            acc01 = __builtin_amdgcn_mfma_f32_16x16x32_bf16(f0.s, B1, acc01, 0, 0, 0);
            accD0 = __builtin_amdgcn_mfma_f32_16x16x32_bf16(f0.s, ones, accD0, 0, 0, 0);
            acc10 = __builtin_amdgcn_mfma_f32_16x16x32_bf16(f1.s, B0, acc10, 0, 0, 0);
            acc11 = __builtin_amdgcn_mfma_f32_16x16x32_bf16(f1.s, B1, acc11, 0, 0, 0);
            accD1 = __builtin_amdgcn_mfma_f32_16x16x32_bf16(f1.s, ones, accD1, 0, 0, 0);
        }
    }

    float* myc = &cmb[h][l][0];
    if (js == 1) {
        *(f32x4*)&myc[0]  = acc00; *(f32x4*)&myc[4]  = acc01;
        *(f32x4*)&myc[8]  = acc10; *(f32x4*)&myc[12] = acc11;
        *(f32x4*)&myc[16] = accD0; *(f32x4*)&myc[20] = accD1;
    }
    __syncthreads();
    if (js == 0) {
        f32x4 o00 = *(const f32x4*)&myc[0],  o01 = *(const f32x4*)&myc[4];
        f32x4 o10 = *(const f32x4*)&myc[8],  o11 = *(const f32x4*)&myc[12];
        f32x4 oD0 = *(const f32x4*)&myc[16], oD1 = *(const f32x4*)&myc[20];
        #pragma unroll
        for (int r = 0; r < 4; ++r) {
            int ir0 = i0 + q * 4 + r;
            int ir1 = i0 + 16 + q * 4 + r;
            float inv0 = 1.0f / (accD0[r] + oD0[r]);
            float inv1 = 1.0f / (accD1[r] + oD1[r]);
            size_t ba0 = ((size_t)(b * NN + ir0)) * (HH * DD) + h * DD;
            size_t ba1 = ((size_t)(b * NN + ir1)) * (HH * DD) + h * DD;
            out[ba0 + ml]      = (acc00[r] + o00[r]) * inv0;
            out[ba0 + 16 + ml] = (acc01[r] + o01[r]) * inv0;
            out[ba1 + ml]      = (acc10[r] + o10[r]) * inv1;
            out[ba1 + 16 + ml] = (acc11[r] + o11[r]) * inv1;
        }
    }
}

extern "C" void kernel_launch(void* const* d_in, const int* in_sizes, int n_in,
                              void* d_out, int out_size, void* d_ws, size_t ws_size,
                              hipStream_t stream) {
    (void)in_sizes; (void)n_in; (void)out_size; (void)ws_size;
    const float* x   = (const float*)d_in[0];
    const int*   adj = (const int*)d_in[1];
    const float* W   = (const float*)d_in[2];
    const float* a   = (const float*)d_in[3];
    float* out = (float*)d_out;

    char* ws = (char*)d_ws;
    unsigned short* whT2 = (unsigned short*)ws;                          // 4 MB
    float*    esrc  = (float*)(ws + (4u << 20));                         // 256 KB
    unsigned* ejP   = (unsigned*)(ws + (4u << 20) + (256u << 10));       // 256 KB
    unsigned* bitsG = (unsigned*)(ws + (4u << 20) + (512u << 10));       // 2 MB

    ekadj_kernel<<<dim3(2560), dim3(256), 0, stream>>>(x, adj, W, a,
                                                       esrc, ejP, bitsG);
    whk_kernel  <<<dim3(512),  dim3(256), 0, stream>>>(x, W, whT2);
    attn_kernel <<<dim3(256),  dim3(1024), 0, stream>>>(whT2, esrc, ejP, bitsG, out);
}

// Round 4
// 185.348 us; speedup vs baseline: 1.0765x; 1.0765x over previous
//
#include <hip/hip_runtime.h>

#define BB 4
#define NN 2048
#define INF 256
#define HH 8
#define DD 32
#define LOG2E 1.4426950408889634f

typedef __attribute__((ext_vector_type(8))) short short8;
typedef __attribute__((ext_vector_type(4))) float f32x4;

__device__ __forceinline__ unsigned short bf16_rne(float v) {
    unsigned b = __float_as_uint(v);
    return (unsigned short)((b + 0x7fffu + ((b >> 16) & 1u)) >> 16);
}
__device__ __forceinline__ unsigned short bf16_rhu(float v) {
    return (unsigned short)((__float_as_uint(v) + 0x8000u) >> 16);
}

// prep: role = bid % 6.
//  role 0 (512): whk  — Wh GEMM -> whT2 bf16 (W->LDS bf16 transpose inline)
//  role 1 (512): ek   — fp32 e-dots -> esrc (log2-scaled) + ejP packed
//  role 2..5 (2048): adjbits — 1 row/wave; 32 loads in flight THEN ballots,
//                    results collected to lanes, one 256B coalesced store.
__global__ __launch_bounds__(256) void prep_kernel(
    const float* __restrict__ x, const int* __restrict__ adj,
    const float* __restrict__ W, const float* __restrict__ a,
    unsigned short* __restrict__ whT2, float* __restrict__ esrc,
    unsigned* __restrict__ ejP, unsigned* __restrict__ bitsG)
{
    __shared__ __align__(16) unsigned short smem[64 * 264 * 2];
    const int bid = blockIdx.x, t = threadIdx.x;
    const int role = bid % 6, id6 = bid / 6;

    if (role >= 2) {                       // ---- adjbits ----
        const int id = id6 * 4 + (role - 2);            // 0..2047
        const int wv = t >> 6, l = t & 63;
        const int row = id * 4 + wv;                    // global (b*N + i) row
        const int* ap = adj + (size_t)row * NN;
        int vreg[32];
        #pragma unroll
        for (int c = 0; c < 32; ++c) vreg[c] = ap[c * 64 + l];   // 32 in flight
        unsigned myw = 0;
        #pragma unroll
        for (int c = 0; c < 32; ++c) {
            unsigned long long m = __ballot(vreg[c] != 0);
            unsigned sel = (l & 1) ? (unsigned)(m >> 32) : (unsigned)m;
            myw = ((l >> 1) == c) ? sel : myw;
        }
        bitsG[(size_t)row * 64 + l] = myw;              // 256B coalesced
        return;
    }

    if (role == 0) {                       // ---- whk ----
        unsigned short* xb = smem;                       // [64][264]
        unsigned short* wb = smem + 64 * 264;            // [64][264]
        const int hp = id6 & 3, tl = (id6 >> 2) & 31, b = id6 >> 7;
        const int n0 = tl * 64;

        #pragma unroll
        for (int p = 0; p < 16; ++p) {                   // x tile -> bf16 LDS
            int flat = p * 1024 + t * 4;
            int row = flat >> 8, col = flat & 255;
            f32x4 g = *(const f32x4*)&x[((size_t)(b * NN + n0 + row)) * INF + col];
            unsigned a0 = __float_as_uint(g[0]) + 0x8000u;
            unsigned a1 = __float_as_uint(g[1]) + 0x8000u;
            unsigned a2 = __float_as_uint(g[2]) + 0x8000u;
            unsigned a3 = __float_as_uint(g[3]) + 0x8000u;
            uint2 pk;
            pk.x = __builtin_amdgcn_perm(a1, a0, 0x07060302u);
            pk.y = __builtin_amdgcn_perm(a3, a2, 0x07060302u);
            *(uint2*)&xb[row * 264 + col] = pk;
        }
        #pragma unroll
        for (int p = 0; p < 16; ++p) {                   // W slice (fp32) -> wb^T bf16
            int flat = p * 1024 + t * 4;                 // 16384 floats = 2 heads
            int h2 = flat >> 13, rem = flat & 8191;
            int f = rem >> 5, d0 = rem & 31;
            f32x4 g = *(const f32x4*)&W[(((size_t)(hp * 2 + h2)) * INF + f) * DD + d0];
            #pragma unroll
            for (int i = 0; i < 4; ++i)
                wb[(h2 * 32 + d0 + i) * 264 + f] = bf16_rhu(g[i]);
        }
        __syncthreads();

        const int w = t >> 6, l = t & 63;
        const int ml = l & 15, q = l >> 4;
        f32x4 acc[4] = {};
        const unsigned short* apx = &xb[(w * 16 + ml) * 264 + q * 8];
        #pragma unroll
        for (int k0 = 0; k0 < INF; k0 += 32) {
            short8 A = *(const short8*)&apx[k0];
            #pragma unroll
            for (int c16 = 0; c16 < 4; ++c16) {
                short8 Bf = *(const short8*)&wb[(c16 * 16 + ml) * 264 + q * 8 + k0];
                acc[c16] = __builtin_amdgcn_mfma_f32_16x16x32_bf16(A, Bf, acc[c16], 0, 0, 0);
            }
        }
        __syncthreads();
        unsigned short* ldsC = xb;                       // [64 col][72 row]
        #pragma unroll
        for (int c16 = 0; c16 < 4; ++c16)
            #pragma unroll
            for (int r = 0; r < 4; ++r) {
                int col = c16 * 16 + ml;
                int rt  = w * 16 + q * 4 + r;
                ldsC[col * 72 + rt] = bf16_rhu(acc[c16][r]);
            }
        __syncthreads();
        #pragma unroll
        for (int p = 0; p < 2; ++p) {
            int g = p * 256 + t;
            int d = g & 31, jo = (g >> 5) & 7, h2 = g >> 8;
            short8 vv = *(const short8*)&ldsC[(h2 * 32 + d) * 72 + jo * 8];
            int bh = b * 8 + hp * 2 + h2;
            *(short8*)&whT2[(((size_t)bh * 256 + tl * 8 + jo) * 32 + d) * 8] = vv;
        }
        return;
    }

    // ---- role 1: ek ----
    float* xs    = (float*)smem;                         // [16][260]
    float* weld2 = (float*)smem + 16 * 260;              // [c=f>>4][k*16+fi]
    const int tile = id6 & 127, b = id6 >> 7;
    const int n0 = tile * 16;

    #pragma unroll
    for (int p = 0; p < 4; ++p) {
        int flat = p * 1024 + t * 4;
        int row = flat >> 8, col = flat & 255;
        f32x4 g = *(const f32x4*)&x[((size_t)(b * NN + n0 + row)) * INF + col];
        *(f32x4*)&xs[row * 260 + col] = g;
    }
    {
        const int f = t;
        #pragma unroll
        for (int h = 0; h < 8; ++h) {
            const float* wr = W + ((size_t)(h * INF + f)) * DD;
            float s0 = 0.f, s1 = 0.f;
            #pragma unroll
            for (int d = 0; d < DD; ++d) {
                float wv = wr[d];
                s0 += wv * a[h * 2 * DD + d];
                s1 += wv * a[h * 2 * DD + DD + d];
            }
            weld2[(f >> 4) * 260 + h * 16 + (f & 15)]       = s0 * LOG2E;
            weld2[(f >> 4) * 260 + (h + 8) * 16 + (f & 15)] = s1 * LOG2E;
        }
    }
    __syncthreads();

    const int row = t >> 4, cc = t & 15;
    f32x4 xv[4];
    #pragma unroll
    for (int i = 0; i < 4; ++i)
        xv[i] = *(const f32x4*)&xs[row * 260 + cc * 16 + i * 4];

    float keep = 0.f;
    #pragma unroll
    for (int k = 0; k < 16; ++k) {
        float s = 0.f;
        #pragma unroll
        for (int i = 0; i < 4; ++i) {
            f32x4 w4 = *(const f32x4*)&weld2[cc * 260 + k * 16 + i * 4];
            s += xv[i][0]*w4[0] + xv[i][1]*w4[1] + xv[i][2]*w4[2] + xv[i][3]*w4[3];
        }
        s += __shfl_xor(s, 1, 64);
        s += __shfl_xor(s, 2, 64);
        s += __shfl_xor(s, 4, 64);
        s += __shfl_xor(s, 8, 64);
        keep = (cc == k) ? s : keep;
    }
    const int n = n0 + row;
    if (cc < 8) {
        esrc[(b * 8 + cc) * NN + n] = keep;
    } else {
        float Ej  = __builtin_amdgcn_exp2f(keep);
        float Ej5 = __builtin_amdgcn_exp2f(0.2f * keep);
        ejP[(b * 8 + (cc - 8)) * NN + n] =
            ((unsigned)bf16_rne(Ej) << 16) | (unsigned)bf16_rne(Ej5);
    }
}

// attn: 1024 blocks x 512 thr (8 waves = 4 heads x 2 j-halves), R=1 (16 i-rows).
// 4 blocks/CU -> 32 waves/CU (100% occupancy), VGPR budget 64, no main-loop
// barriers. p' = max(Ej, Fj*Gi), Gi = 2^(-0.8 ei) (per-row scale cancels).
__global__ __launch_bounds__(512, 8) void attn_kernel(
    const unsigned short* __restrict__ whT2, const float* __restrict__ esrc,
    const unsigned* __restrict__ ejP, const unsigned* __restrict__ bitsG,
    float* __restrict__ out)
{
    __shared__ __align__(16) float cmb[4][64][13];   // 13: odd stride, 13.3KB
    const int t = threadIdx.x, v = t >> 6, l = t & 63;
    const int h4 = v & 3, js = v >> 2;
    const int ml = l & 15, q = l >> 4;
    const int bid = blockIdx.x;
    const int hg = bid & 1, it = (bid >> 1) & 127, b = bid >> 8;
    const int h = hg * 4 + h4;
    const int i0 = it * 16;
    const int bh = b * HH + h;

    const float ei = esrc[bh * NN + i0 + ml];
    const float Gi = __builtin_amdgcn_exp2f(-0.8f * ei);

    const unsigned* epP = ejP + bh * NN + js * 1024;
    const unsigned short* whb = whT2 + ((size_t)bh * 256 + js * 128) * 256;
    const unsigned* mb = bitsG + ((size_t)(b * NN + i0 + ml)) * 64 + js * 32;

    const short8 ones = {0x3F80, 0x3F80, 0x3F80, 0x3F80,
                         0x3F80, 0x3F80, 0x3F80, 0x3F80};
    f32x4 accP = {}, accQ = {}, accD = {};

    for (int c = 0; c < 8; ++c) {
        unsigned mw[4];
        *(uint4*)mw = *(const uint4*)&mb[c * 4];
        const unsigned* epc = epP + c * 128;
        #pragma unroll
        for (int k = 0; k < 4; ++k) {
            const int jb = k * 32 + q * 8;
            uint4 epA = *(const uint4*)&epc[jb];
            uint4 epB = *(const uint4*)&epc[jb + 4];
            const unsigned short* wp = whb + (size_t)(c * 16 + k * 4 + q) * 256;
            short8 B0 = *(const short8*)&wp[ml * 8];
            short8 B1 = *(const short8*)&wp[(16 + ml) * 8];
            unsigned st = mw[k] >> (q * 8);
            union { unsigned u[4]; short8 s; } f0;
            const unsigned* ea = &epA.x;
            const unsigned* eb = &epB.x;
            #pragma unroll
            for (int pp = 0; pp < 4; ++pp) {
                unsigned pkA = (pp < 2) ? ea[2 * pp]     : eb[2 * pp - 4];
                unsigned pkB = (pp < 2) ? ea[2 * pp + 1] : eb[2 * pp - 3];
                float EjA = __uint_as_float(pkA & 0xffff0000u);
                float FjA = __uint_as_float(pkA << 16);
                float EjB = __uint_as_float(pkB & 0xffff0000u);
                float FjB = __uint_as_float(pkB << 16);
                unsigned mA = (unsigned)__builtin_amdgcn_sbfe(st, 2 * pp, 1);
                unsigned mB = (unsigned)__builtin_amdgcn_sbfe(st, 2 * pp + 1, 1);
                float pA = fmaxf(EjA, FjA * Gi);
                float pB = fmaxf(EjB, FjB * Gi);
                f0.u[pp] = __builtin_amdgcn_perm(__float_as_uint(pB) & mB,
                                                 __float_as_uint(pA) & mA,
                                                 0x07060302u);
            }
            accP = __builtin_amdgcn_mfma_f32_16x16x32_bf16(f0.s, B0, accP, 0, 0, 0);
            accQ = __builtin_amdgcn_mfma_f32_16x16x32_bf16(f0.s, B1, accQ, 0, 0, 0);
            accD = __builtin_amdgcn_mfma_f32_16x16x32_bf16(f0.s, ones, accD, 0, 0, 0);
        }
    }

    float* myc = &cmb[h4][l][0];
    if (js == 1) {
        *(f32x4*)&myc[0] = accP;
        *(f32x4*)&myc[4] = accQ;
        *(f32x4*)&myc[8] = accD;
    }
    __syncthreads();
    if (js == 0) {
        f32x4 oP = *(const f32x4*)&myc[0];
        f32x4 oQ = *(const f32x4*)&myc[4];
        f32x4 oD = *(const f32x4*)&myc[8];
        #pragma unroll
        for (int r = 0; r < 4; ++r) {
            int ir = i0 + q * 4 + r;
            float inv = 1.0f / (accD[r] + oD[r]);
            size_t ba = ((size_t)(b * NN + ir)) * (HH * DD) + h * DD;
            out[ba + ml]      = (accP[r] + oP[r]) * inv;
            out[ba + 16 + ml] = (accQ[r] + oQ[r]) * inv;
        }
    }
}

extern "C" void kernel_launch(void* const* d_in, const int* in_sizes, int n_in,
                              void* d_out, int out_size, void* d_ws, size_t ws_size,
                              hipStream_t stream) {
    (void)in_sizes; (void)n_in; (void)out_size; (void)ws_size;
    const float* x   = (const float*)d_in[0];
    const int*   adj = (const int*)d_in[1];
    const float* W   = (const float*)d_in[2];
    const float* a   = (const float*)d_in[3];
    float* out = (float*)d_out;

    char* ws = (char*)d_ws;
    unsigned short* whT2 = (unsigned short*)ws;                          // 4 MB
    float*    esrc  = (float*)(ws + (4u << 20));                         // 256 KB
    unsigned* ejP   = (unsigned*)(ws + (4u << 20) + (256u << 10));       // 256 KB
    unsigned* bitsG = (unsigned*)(ws + (4u << 20) + (512u << 10));       // 2 MB

    prep_kernel<<<dim3(3072), dim3(256), 0, stream>>>(x, adj, W, a,
                                                      whT2, esrc, ejP, bitsG);
    attn_kernel<<<dim3(1024), dim3(512), 0, stream>>>(whT2, esrc, ejP, bitsG, out);
}

// Round 6
// 152.494 us; speedup vs baseline: 1.3084x; 1.2154x over previous
//
#include <hip/hip_runtime.h>

#define BB 4
#define NN 2048
#define INF 256
#define HH 8
#define DD 32
#define LOG2E 1.4426950408889634f

typedef __attribute__((ext_vector_type(8))) short short8;
typedef __attribute__((ext_vector_type(4))) float f32x4;
typedef __attribute__((address_space(3))) unsigned as3_u32;
typedef __attribute__((address_space(1))) const unsigned as1_u32;

__device__ __forceinline__ unsigned short bf16_rne(float v) {
    unsigned b = __float_as_uint(v);
    return (unsigned short)((b + 0x7fffu + ((b >> 16) & 1u)) >> 16);
}
__device__ __forceinline__ unsigned short bf16_rhu(float v) {
    return (unsigned short)((__float_as_uint(v) + 0x8000u) >> 16);
}

// adjprep: zero-LDS kernel. bid<2048: adjbits (1 row/wave, 32 loads in flight,
// ballots on regs, one coalesced 256B store). bid>=2048: we dots (16 blocks).
__global__ __launch_bounds__(256) void adjprep_kernel(
    const int* __restrict__ adj, const float* __restrict__ W,
    const float* __restrict__ a, unsigned* __restrict__ bitsG,
    float* __restrict__ we_g)
{
    const int bid = blockIdx.x, t = threadIdx.x;
    if (bid < 2048) {
        const int wv = t >> 6, l = t & 63;
        const int row = bid * 4 + wv;                   // global (b*N + i) row
        const int* ap = adj + (size_t)row * NN;
        int vreg[32];
        #pragma unroll
        for (int c = 0; c < 32; ++c) vreg[c] = ap[c * 64 + l];   // 32 in flight
        unsigned myw = 0;
        #pragma unroll
        for (int c = 0; c < 32; ++c) {
            unsigned long long m = __ballot(vreg[c] != 0);
            unsigned sel = (l & 1) ? (unsigned)(m >> 32) : (unsigned)m;
            myw = ((l >> 1) == c) ? sel : myw;
        }
        bitsG[(size_t)row * 64 + l] = myw;              // 256B coalesced
        return;
    }
    const int k = bid - 2048;                           // 0..15
    const int h = k & 7, sel = k >> 3;
    const float* wr = W + ((size_t)(h * INF + t)) * DD;
    const float* av = a + h * 2 * DD + sel * DD;
    float acc = 0.f;
    #pragma unroll
    for (int d = 0; d < DD; ++d) acc += wr[d] * av[d];
    we_g[k * INF + t] = acc * LOG2E;
}

// prepw: role = bid&1. role0 (512): whk GEMM -> whT2 bf16 [bh][j/8][d][8].
// role1 (512): ek -> esrc (log2-scaled) + ejP packed (reads we_g).
__global__ __launch_bounds__(256) void prepw_kernel(
    const float* __restrict__ x, const float* __restrict__ W,
    const float* __restrict__ we_g, unsigned short* __restrict__ whT2,
    float* __restrict__ esrc, unsigned* __restrict__ ejP)
{
    __shared__ __align__(16) unsigned short smem[64 * 264 * 2];
    const int bid = blockIdx.x, t = threadIdx.x;
    const int role = bid & 1, id = bid >> 1;

    if (role == 0) {                       // ---- whk ----
        unsigned short* xb = smem;                       // [64][264]
        unsigned short* wb = smem + 64 * 264;            // [64][264]
        const int hp = id & 3, tl = (id >> 2) & 31, b = id >> 7;
        const int n0 = tl * 64;

        #pragma unroll
        for (int p = 0; p < 16; ++p) {                   // x tile -> bf16 LDS
            int flat = p * 1024 + t * 4;
            int row = flat >> 8, col = flat & 255;
            f32x4 g = *(const f32x4*)&x[((size_t)(b * NN + n0 + row)) * INF + col];
            unsigned a0 = __float_as_uint(g[0]) + 0x8000u;
            unsigned a1 = __float_as_uint(g[1]) + 0x8000u;
            unsigned a2 = __float_as_uint(g[2]) + 0x8000u;
            unsigned a3 = __float_as_uint(g[3]) + 0x8000u;
            uint2 pk;
            pk.x = __builtin_amdgcn_perm(a1, a0, 0x07060302u);
            pk.y = __builtin_amdgcn_perm(a3, a2, 0x07060302u);
            *(uint2*)&xb[row * 264 + col] = pk;
        }
        #pragma unroll
        for (int p = 0; p < 16; ++p) {                   // W slice (fp32) -> wb^T bf16
            int flat = p * 1024 + t * 4;                 // 16384 floats = 2 heads
            int h2 = flat >> 13, rem = flat & 8191;
            int f = rem >> 5, d0 = rem & 31;
            f32x4 g = *(const f32x4*)&W[(((size_t)(hp * 2 + h2)) * INF + f) * DD + d0];
            #pragma unroll
            for (int i = 0; i < 4; ++i)
                wb[(h2 * 32 + d0 + i) * 264 + f] = bf16_rhu(g[i]);
        }
        __syncthreads();

        const int w = t >> 6, l = t & 63;
        const int ml = l & 15, q = l >> 4;
        f32x4 acc[4] = {};
        const unsigned short* apx = &xb[(w * 16 + ml) * 264 + q * 8];
        #pragma unroll
        for (int k0 = 0; k0 < INF; k0 += 32) {
            short8 A = *(const short8*)&apx[k0];
            #pragma unroll
            for (int c16 = 0; c16 < 4; ++c16) {
                short8 Bf = *(const short8*)&wb[(c16 * 16 + ml) * 264 + q * 8 + k0];
                acc[c16] = __builtin_amdgcn_mfma_f32_16x16x32_bf16(A, Bf, acc[c16], 0, 0, 0);
            }
        }
        __syncthreads();
        unsigned short* ldsC = xb;                       // [64 col][72 row]
        #pragma unroll
        for (int c16 = 0; c16 < 4; ++c16)
            #pragma unroll
            for (int r = 0; r < 4; ++r) {
                int col = c16 * 16 + ml;
                int rt  = w * 16 + q * 4 + r;
                ldsC[col * 72 + rt] = bf16_rhu(acc[c16][r]);
            }
        __syncthreads();
        #pragma unroll
        for (int p = 0; p < 2; ++p) {
            int g = p * 256 + t;
            int d = g & 31, jo = (g >> 5) & 7, h2 = g >> 8;
            short8 vv = *(const short8*)&ldsC[(h2 * 32 + d) * 72 + jo * 8];
            int bh = b * 8 + hp * 2 + h2;
            *(short8*)&whT2[(((size_t)bh * 256 + tl * 8 + jo) * 32 + d) * 8] = vv;
        }
        return;
    }

    // ---- ek ----
    float* xs    = (float*)smem;                         // [16][260]
    float* weld2 = (float*)smem + 16 * 260;              // [c=f>>4][k*16+fi]
    const int tile = id & 127, b = id >> 7;
    const int n0 = tile * 16;

    #pragma unroll
    for (int p = 0; p < 4; ++p) {
        int flat = p * 1024 + t * 4;
        int row = flat >> 8, col = flat & 255;
        f32x4 g = *(const f32x4*)&x[((size_t)(b * NN + n0 + row)) * INF + col];
        *(f32x4*)&xs[row * 260 + col] = g;
    }
    #pragma unroll
    for (int p = 0; p < 4; ++p) {                        // we_g: 4096 floats
        int flat = p * 1024 + t * 4;
        int k = flat >> 8, f = flat & 255;
        f32x4 g = *(const f32x4*)&we_g[flat];
        *(f32x4*)&weld2[(f >> 4) * 260 + k * 16 + (f & 15)] = g;
    }
    __syncthreads();

    const int row = t >> 4, cc = t & 15;
    f32x4 xv[4];
    #pragma unroll
    for (int i = 0; i < 4; ++i)
        xv[i] = *(const f32x4*)&xs[row * 260 + cc * 16 + i * 4];

    float keep = 0.f;
    #pragma unroll
    for (int k = 0; k < 16; ++k) {
        float s = 0.f;
        #pragma unroll
        for (int i = 0; i < 4; ++i) {
            f32x4 w4 = *(const f32x4*)&weld2[cc * 260 + k * 16 + i * 4];
            s += xv[i][0]*w4[0] + xv[i][1]*w4[1] + xv[i][2]*w4[2] + xv[i][3]*w4[3];
        }
        s += __shfl_xor(s, 1, 64);
        s += __shfl_xor(s, 2, 64);
        s += __shfl_xor(s, 4, 64);
        s += __shfl_xor(s, 8, 64);
        keep = (cc == k) ? s : keep;
    }
    const int n = n0 + row;
    if (cc < 8) {
        esrc[(b * 8 + cc) * NN + n] = keep;
    } else {
        float Ej  = __builtin_amdgcn_exp2f(keep);
        float Ej5 = __builtin_amdgcn_exp2f(0.2f * keep);
        ejP[(b * 8 + (cc - 8)) * NN + n] =
            ((unsigned)bf16_rne(Ej) << 16) | (unsigned)bf16_rne(Ej5);
    }
}

// attn: 512 blocks x 512 thr. block = (b, h, 128-row group); wave = 16 rows x
// full j (2048) -> denominator wave-local, no combine. whb (8KB) + ejP (512B)
// per-128-j chunk staged to LDS via global_load_lds, double-buffered, 1
// barrier/chunk; all 8 waves reuse. Masks straight from bitsG (L2).
// p' = max(Ej, Fj*Gi), Gi = 2^(-0.8 ei): per-row scale cancels in softmax.
__global__ __launch_bounds__(512, 4) void attn_kernel(
    const unsigned short* __restrict__ whT2, const float* __restrict__ esrc,
    const unsigned* __restrict__ ejP, const unsigned* __restrict__ bitsG,
    float* __restrict__ out)
{
    __shared__ __align__(16) unsigned short whs[2][4096];   // [buf][8KB chunk]
    __shared__ __align__(16) unsigned eps[2][128];          // [buf][128 j]
    const int t = threadIdx.x, w = t >> 6, l = t & 63;
    const int ml = l & 15, q = l >> 4;
    const int obid = blockIdx.x;
    const int bid = (obid & 7) * 64 + (obid >> 3);          // XCD swizzle (512=8*64)
    const int ig = bid & 15, h = (bid >> 4) & 7, b = bid >> 7;
    const int bh = b * HH + h;
    const int i0 = ig * 128 + w * 16;                       // wave's 16 rows

    const float ei = esrc[bh * NN + i0 + ml];
    const float Gi = __builtin_amdgcn_exp2f(-0.8f * ei);

    const unsigned short* whb = whT2 + (size_t)bh * (256 * 256);  // [jg][d][8]
    const unsigned* epRow = ejP + bh * NN;
    const unsigned* mbase = bitsG + ((size_t)(b * NN + i0 + ml)) * 64;

    auto stage = [&](int c, int buf) {
        // whb chunk c: 8KB contiguous; wave w stages bytes w*1024..+1024
        const char* g = (const char*)whb + c * 8192 + w * 1024 + l * 16;
        unsigned short* ld = &whs[buf][w * 512];            // wave-uniform base
        __builtin_amdgcn_global_load_lds((as1_u32*)g, (as3_u32*)ld, 16, 0, 0);
        if (w == 0) {                                       // ep chunk: 512B
            const unsigned* g1 = epRow + c * 128 + l;
            __builtin_amdgcn_global_load_lds((as1_u32*)g1, (as3_u32*)&eps[buf][0], 4, 0, 0);
            const unsigned* g2 = g1 + 64;
            __builtin_amdgcn_global_load_lds((as1_u32*)g2, (as3_u32*)&eps[buf][64], 4, 0, 0);
        }
    };

    const short8 ones = {0x3F80, 0x3F80, 0x3F80, 0x3F80,
                         0x3F80, 0x3F80, 0x3F80, 0x3F80};
    f32x4 accP = {}, accQ = {}, accD = {};

    stage(0, 0);
    uint4 mrow = *(const uint4*)&mbase[0];
    for (int c = 0; c < 16; ++c) {
        __syncthreads();                  // stage(c) complete; buf^1 free
        if (c < 15) stage(c + 1, (c + 1) & 1);
        const int buf = c & 1;
        const uint4 mcur = mrow;
        if (c < 15) mrow = *(const uint4*)&mbase[(c + 1) * 4];   // prefetch
        const unsigned mw[4] = {mcur.x, mcur.y, mcur.z, mcur.w};
        #pragma unroll
        for (int k = 0; k < 4; ++k) {
            const unsigned short* wp = &whs[buf][(k * 4 + q) * 256];
            short8 B0 = *(const short8*)&wp[ml * 8];
            short8 B1 = *(const short8*)&wp[(16 + ml) * 8];
            uint4 epA = *(const uint4*)&eps[buf][k * 32 + q * 8];
            uint4 epB = *(const uint4*)&eps[buf][k * 32 + q * 8 + 4];
            unsigned st = mw[k] >> (q * 8);
            union { unsigned u[4]; short8 s; } f0;
            const unsigned* ea = &epA.x;
            const unsigned* eb = &epB.x;
            #pragma unroll
            for (int pp = 0; pp < 4; ++pp) {
                unsigned pkA = (pp < 2) ? ea[2 * pp]     : eb[2 * pp - 4];
                unsigned pkB = (pp < 2) ? ea[2 * pp + 1] : eb[2 * pp - 3];
                float EjA = __uint_as_float(pkA & 0xffff0000u);
                float FjA = __uint_as_float(pkA << 16);
                float EjB = __uint_as_float(pkB & 0xffff0000u);
                float FjB = __uint_as_float(pkB << 16);
                unsigned mA = (unsigned)__builtin_amdgcn_sbfe(st, 2 * pp, 1);
                unsigned mB = (unsigned)__builtin_amdgcn_sbfe(st, 2 * pp + 1, 1);
                float pA = fmaxf(EjA, FjA * Gi);
                float pB = fmaxf(EjB, FjB * Gi);
                f0.u[pp] = __builtin_amdgcn_perm(__float_as_uint(pB) & mB,
                                                 __float_as_uint(pA) & mA,
                                                 0x07060302u);
            }
            accP = __builtin_amdgcn_mfma_f32_16x16x32_bf16(f0.s, B0, accP, 0, 0, 0);
            accQ = __builtin_amdgcn_mfma_f32_16x16x32_bf16(f0.s, B1, accQ, 0, 0, 0);
            accD = __builtin_amdgcn_mfma_f32_16x16x32_bf16(f0.s, ones, accD, 0, 0, 0);
        }
    }

    #pragma unroll
    for (int r = 0; r < 4; ++r) {
        int ir = i0 + q * 4 + r;
        float inv = 1.0f / accD[r];
        size_t ba = ((size_t)(b * NN + ir)) * (HH * DD) + h * DD;
        out[ba + ml]      = accP[r] * inv;
        out[ba + 16 + ml] = accQ[r] * inv;
    }
}

extern "C" void kernel_launch(void* const* d_in, const int* in_sizes, int n_in,
                              void* d_out, int out_size, void* d_ws, size_t ws_size,
                              hipStream_t stream) {
    (void)in_sizes; (void)n_in; (void)out_size; (void)ws_size;
    const float* x   = (const float*)d_in[0];
    const int*   adj = (const int*)d_in[1];
    const float* W   = (const float*)d_in[2];
    const float* a   = (const float*)d_in[3];
    float* out = (float*)d_out;

    char* ws = (char*)d_ws;
    unsigned short* whT2 = (unsigned short*)ws;                          // 4 MB
    float*    esrc  = (float*)(ws + (4u << 20));                         // 256 KB
    unsigned* ejP   = (unsigned*)(ws + (4u << 20) + (256u << 10));       // 256 KB
    unsigned* bitsG = (unsigned*)(ws + (4u << 20) + (512u << 10));       // 2 MB
    float*    we_g  = (float*)(ws + (4u << 20) + (512u << 10) + (2u << 20)); // 16 KB

    adjprep_kernel<<<dim3(2064), dim3(256), 0, stream>>>(adj, W, a, bitsG, we_g);
    prepw_kernel  <<<dim3(1024), dim3(256), 0, stream>>>(x, W, we_g, whT2, esrc, ejP);
    attn_kernel   <<<dim3(512),  dim3(512), 0, stream>>>(whT2, esrc, ejP, bitsG, out);
}

// Round 7
// 151.666 us; speedup vs baseline: 1.3156x; 1.0055x over previous
//
#include <hip/hip_runtime.h>

#define BB 4
#define NN 2048
#define INF 256
#define HH 8
#define DD 32
#define LOG2E 1.4426950408889634f

typedef __attribute__((ext_vector_type(8))) short short8;
typedef __attribute__((ext_vector_type(4))) float f32x4;
typedef __attribute__((address_space(3))) unsigned as3_u32;
typedef __attribute__((address_space(1))) const unsigned as1_u32;

__device__ __forceinline__ unsigned short bf16_rne(float v) {
    unsigned b = __float_as_uint(v);
    return (unsigned short)((b + 0x7fffu + ((b >> 16) & 1u)) >> 16);
}
__device__ __forceinline__ unsigned short bf16_rhu(float v) {
    return (unsigned short)((__float_as_uint(v) + 0x8000u) >> 16);
}

// adjprep: zero-LDS kernel. bid<2048: adjbits (1 row/wave, 32 loads in flight,
// ballots on regs, one coalesced 256B store). bid>=2048: we dots (16 blocks).
__global__ __launch_bounds__(256) void adjprep_kernel(
    const int* __restrict__ adj, const float* __restrict__ W,
    const float* __restrict__ a, unsigned* __restrict__ bitsG,
    float* __restrict__ we_g)
{
    const int bid = blockIdx.x, t = threadIdx.x;
    if (bid < 2048) {
        const int wv = t >> 6, l = t & 63;
        const int row = bid * 4 + wv;                   // global (b*N + i) row
        const int* ap = adj + (size_t)row * NN;
        int vreg[32];
        #pragma unroll
        for (int c = 0; c < 32; ++c) vreg[c] = ap[c * 64 + l];   // 32 in flight
        unsigned myw = 0;
        #pragma unroll
        for (int c = 0; c < 32; ++c) {
            unsigned long long m = __ballot(vreg[c] != 0);
            unsigned sel = (l & 1) ? (unsigned)(m >> 32) : (unsigned)m;
            myw = ((l >> 1) == c) ? sel : myw;
        }
        bitsG[(size_t)row * 64 + l] = myw;              // 256B coalesced
        return;
    }
    const int k = bid - 2048;                           // 0..15
    const int h = k & 7, sel = k >> 3;
    const float* wr = W + ((size_t)(h * INF + t)) * DD;
    const float* av = a + h * 2 * DD + sel * DD;
    float acc = 0.f;
    #pragma unroll
    for (int d = 0; d < DD; ++d) acc += wr[d] * av[d];
    we_g[k * INF + t] = acc * LOG2E;
}

// prepw: role = bid&1. role0 (512): whk GEMM -> whT2 bf16 [bh][j/8][d][8].
// role1 (512): ek -> esrc (log2-scaled) + ejP packed (reads we_g).
__global__ __launch_bounds__(256) void prepw_kernel(
    const float* __restrict__ x, const float* __restrict__ W,
    const float* __restrict__ we_g, unsigned short* __restrict__ whT2,
    float* __restrict__ esrc, unsigned* __restrict__ ejP)
{
    __shared__ __align__(16) unsigned short smem[64 * 264 * 2];
    const int bid = blockIdx.x, t = threadIdx.x;
    const int role = bid & 1, id = bid >> 1;

    if (role == 0) {                       // ---- whk ----
        unsigned short* xb = smem;                       // [64][264]
        unsigned short* wb = smem + 64 * 264;            // [64][264]
        const int hp = id & 3, tl = (id >> 2) & 31, b = id >> 7;
        const int n0 = tl * 64;

        #pragma unroll
        for (int p = 0; p < 16; ++p) {                   // x tile -> bf16 LDS
            int flat = p * 1024 + t * 4;
            int row = flat >> 8, col = flat & 255;
            f32x4 g = *(const f32x4*)&x[((size_t)(b * NN + n0 + row)) * INF + col];
            unsigned a0 = __float_as_uint(g[0]) + 0x8000u;
            unsigned a1 = __float_as_uint(g[1]) + 0x8000u;
            unsigned a2 = __float_as_uint(g[2]) + 0x8000u;
            unsigned a3 = __float_as_uint(g[3]) + 0x8000u;
            uint2 pk;
            pk.x = __builtin_amdgcn_perm(a1, a0, 0x07060302u);
            pk.y = __builtin_amdgcn_perm(a3, a2, 0x07060302u);
            *(uint2*)&xb[row * 264 + col] = pk;
        }
        #pragma unroll
        for (int p = 0; p < 16; ++p) {                   // W slice (fp32) -> wb^T bf16
            int flat = p * 1024 + t * 4;                 // 16384 floats = 2 heads
            int h2 = flat >> 13, rem = flat & 8191;
            int f = rem >> 5, d0 = rem & 31;
            f32x4 g = *(const f32x4*)&W[(((size_t)(hp * 2 + h2)) * INF + f) * DD + d0];
            #pragma unroll
            for (int i = 0; i < 4; ++i)
                wb[(h2 * 32 + d0 + i) * 264 + f] = bf16_rhu(g[i]);
        }
        __syncthreads();

        const int w = t >> 6, l = t & 63;
        const int ml = l & 15, q = l >> 4;
        f32x4 acc[4] = {};
        const unsigned short* apx = &xb[(w * 16 + ml) * 264 + q * 8];
        #pragma unroll
        for (int k0 = 0; k0 < INF; k0 += 32) {
            short8 A = *(const short8*)&apx[k0];
            #pragma unroll
            for (int c16 = 0; c16 < 4; ++c16) {
                short8 Bf = *(const short8*)&wb[(c16 * 16 + ml) * 264 + q * 8 + k0];
                acc[c16] = __builtin_amdgcn_mfma_f32_16x16x32_bf16(A, Bf, acc[c16], 0, 0, 0);
            }
        }
        __syncthreads();
        unsigned short* ldsC = xb;                       // [64 col][72 row]
        #pragma unroll
        for (int c16 = 0; c16 < 4; ++c16)
            #pragma unroll
            for (int r = 0; r < 4; ++r) {
                int col = c16 * 16 + ml;
                int rt  = w * 16 + q * 4 + r;
                ldsC[col * 72 + rt] = bf16_rhu(acc[c16][r]);
            }
        __syncthreads();
        #pragma unroll
        for (int p = 0; p < 2; ++p) {
            int g = p * 256 + t;
            int d = g & 31, jo = (g >> 5) & 7, h2 = g >> 8;
            short8 vv = *(const short8*)&ldsC[(h2 * 32 + d) * 72 + jo * 8];
            int bh = b * 8 + hp * 2 + h2;
            *(short8*)&whT2[(((size_t)bh * 256 + tl * 8 + jo) * 32 + d) * 8] = vv;
        }
        return;
    }

    // ---- ek ----
    float* xs    = (float*)smem;                         // [16][260]
    float* weld2 = (float*)smem + 16 * 260;              // [c=f>>4][k*16+fi]
    const int tile = id & 127, b = id >> 7;
    const int n0 = tile * 16;

    #pragma unroll
    for (int p = 0; p < 4; ++p) {
        int flat = p * 1024 + t * 4;
        int row = flat >> 8, col = flat & 255;
        f32x4 g = *(const f32x4*)&x[((size_t)(b * NN + n0 + row)) * INF + col];
        *(f32x4*)&xs[row * 260 + col] = g;
    }
    #pragma unroll
    for (int p = 0; p < 4; ++p) {                        // we_g: 4096 floats
        int flat = p * 1024 + t * 4;
        int k = flat >> 8, f = flat & 255;
        f32x4 g = *(const f32x4*)&we_g[flat];
        *(f32x4*)&weld2[(f >> 4) * 260 + k * 16 + (f & 15)] = g;
    }
    __syncthreads();

    const int row = t >> 4, cc = t & 15;
    f32x4 xv[4];
    #pragma unroll
    for (int i = 0; i < 4; ++i)
        xv[i] = *(const f32x4*)&xs[row * 260 + cc * 16 + i * 4];

    float keep = 0.f;
    #pragma unroll
    for (int k = 0; k < 16; ++k) {
        float s = 0.f;
        #pragma unroll
        for (int i = 0; i < 4; ++i) {
            f32x4 w4 = *(const f32x4*)&weld2[cc * 260 + k * 16 + i * 4];
            s += xv[i][0]*w4[0] + xv[i][1]*w4[1] + xv[i][2]*w4[2] + xv[i][3]*w4[3];
        }
        s += __shfl_xor(s, 1, 64);
        s += __shfl_xor(s, 2, 64);
        s += __shfl_xor(s, 4, 64);
        s += __shfl_xor(s, 8, 64);
        keep = (cc == k) ? s : keep;
    }
    const int n = n0 + row;
    if (cc < 8) {
        esrc[(b * 8 + cc) * NN + n] = keep;
    } else {
        float Ej  = __builtin_amdgcn_exp2f(keep);
        float Ej5 = __builtin_amdgcn_exp2f(0.2f * keep);
        ejP[(b * 8 + (cc - 8)) * NN + n] =
            ((unsigned)bf16_rne(Ej) << 16) | (unsigned)bf16_rne(Ej5);
    }
}

// attn: 1024 blocks x 256 thr (4 waves x 16 rows = 64-row block), 8 blocks/CU
// -> 32 waves/CU. wave = 16 rows x full j; denominator wave-local, no combine.
// whb (8KB) + ejP (512B) per-128-j chunk staged to LDS via global_load_lds,
// double-buffered, 1 barrier/chunk; 4 waves reuse. Masks direct from bitsG.
// p' = max(Ej, Fj*Gi), Gi = 2^(-0.8 ei): per-row scale cancels in softmax.
__global__ __launch_bounds__(256, 8) void attn_kernel(
    const unsigned short* __restrict__ whT2, const float* __restrict__ esrc,
    const unsigned* __restrict__ ejP, const unsigned* __restrict__ bitsG,
    float* __restrict__ out)
{
    __shared__ __align__(16) unsigned short whs[2][4096];   // [buf][8KB chunk]
    __shared__ __align__(16) unsigned eps[2][128];          // [buf][128 j]
    const int t = threadIdx.x, w = t >> 6, l = t & 63;
    const int ml = l & 15, q = l >> 4;
    const int obid = blockIdx.x;
    const int bid = (obid & 7) * 128 + (obid >> 3);         // XCD swizzle (1024=8*128)
    const int ig = bid & 31, h = (bid >> 5) & 7, b = bid >> 8;
    const int bh = b * HH + h;
    const int i0 = ig * 64 + w * 16;                        // wave's 16 rows

    const float ei = esrc[bh * NN + i0 + ml];
    const float Gi = __builtin_amdgcn_exp2f(-0.8f * ei);

    const unsigned short* whb = whT2 + (size_t)bh * (256 * 256);  // [jg][d][8]
    const unsigned* epRow = ejP + bh * NN;
    const unsigned* mbase = bitsG + ((size_t)(b * NN + i0 + ml)) * 64;

    auto stage = [&](int c, int buf) {
        // whb chunk c: 8KB contiguous; wave w stages bytes w*2048..+2048
        const char* g = (const char*)whb + c * 8192 + w * 2048 + l * 16;
        unsigned short* ld = &whs[buf][w * 1024];           // wave-uniform base
        __builtin_amdgcn_global_load_lds((as1_u32*)g, (as3_u32*)ld, 16, 0, 0);
        __builtin_amdgcn_global_load_lds((as1_u32*)(g + 1024), (as3_u32*)(ld + 512), 16, 0, 0);
        if (w == 0) {                                       // ep chunk: 512B
            const unsigned* g1 = epRow + c * 128 + l;
            __builtin_amdgcn_global_load_lds((as1_u32*)g1, (as3_u32*)&eps[buf][0], 4, 0, 0);
            const unsigned* g2 = g1 + 64;
            __builtin_amdgcn_global_load_lds((as1_u32*)g2, (as3_u32*)&eps[buf][64], 4, 0, 0);
        }
    };

    const short8 ones = {0x3F80, 0x3F80, 0x3F80, 0x3F80,
                         0x3F80, 0x3F80, 0x3F80, 0x3F80};
    f32x4 accP = {}, accQ = {}, accD = {};

    stage(0, 0);
    uint4 mrow = *(const uint4*)&mbase[0];
    for (int c = 0; c < 16; ++c) {
        __syncthreads();                  // stage(c) complete; buf^1 free
        if (c < 15) stage(c + 1, (c + 1) & 1);
        const int buf = c & 1;
        const uint4 mcur = mrow;
        if (c < 15) mrow = *(const uint4*)&mbase[(c + 1) * 4];   // prefetch
        const unsigned mw[4] = {mcur.x, mcur.y, mcur.z, mcur.w};
        #pragma unroll
        for (int k = 0; k < 4; ++k) {
            const unsigned short* wp = &whs[buf][(k * 4 + q) * 256];
            short8 B0 = *(const short8*)&wp[ml * 8];
            short8 B1 = *(const short8*)&wp[(16 + ml) * 8];
            uint4 epA = *(const uint4*)&eps[buf][k * 32 + q * 8];
            uint4 epB = *(const uint4*)&eps[buf][k * 32 + q * 8 + 4];
            unsigned st = mw[k] >> (q * 8);
            union { unsigned u[4]; short8 s; } f0;
            const unsigned* ea = &epA.x;
            const unsigned* eb = &epB.x;
            #pragma unroll
            for (int pp = 0; pp < 4; ++pp) {
                unsigned pkA = (pp < 2) ? ea[2 * pp]     : eb[2 * pp - 4];
                unsigned pkB = (pp < 2) ? ea[2 * pp + 1] : eb[2 * pp - 3];
                float EjA = __uint_as_float(pkA & 0xffff0000u);
                float FjA = __uint_as_float(pkA << 16);
                float EjB = __uint_as_float(pkB & 0xffff0000u);
                float FjB = __uint_as_float(pkB << 16);
                unsigned mA = (unsigned)__builtin_amdgcn_sbfe(st, 2 * pp, 1);
                unsigned mB = (unsigned)__builtin_amdgcn_sbfe(st, 2 * pp + 1, 1);
                float pA = fmaxf(EjA, FjA * Gi);
                float pB = fmaxf(EjB, FjB * Gi);
                f0.u[pp] = __builtin_amdgcn_perm(__float_as_uint(pB) & mB,
                                                 __float_as_uint(pA) & mA,
                                                 0x07060302u);
            }
            accP = __builtin_amdgcn_mfma_f32_16x16x32_bf16(f0.s, B0, accP, 0, 0, 0);
            accQ = __builtin_amdgcn_mfma_f32_16x16x32_bf16(f0.s, B1, accQ, 0, 0, 0);
            accD = __builtin_amdgcn_mfma_f32_16x16x32_bf16(f0.s, ones, accD, 0, 0, 0);
        }
    }

    #pragma unroll
    for (int r = 0; r < 4; ++r) {
        int ir = i0 + q * 4 + r;
        float inv = 1.0f / accD[r];
        size_t ba = ((size_t)(b * NN + ir)) * (HH * DD) + h * DD;
        out[ba + ml]      = accP[r] * inv;
        out[ba + 16 + ml] = accQ[r] * inv;
    }
}

extern "C" void kernel_launch(void* const* d_in, const int* in_sizes, int n_in,
                              void* d_out, int out_size, void* d_ws, size_t ws_size,
                              hipStream_t stream) {
    (void)in_sizes; (void)n_in; (void)out_size; (void)ws_size;
    const float* x   = (const float*)d_in[0];
    const int*   adj = (const int*)d_in[1];
    const float* W   = (const float*)d_in[2];
    const float* a   = (const float*)d_in[3];
    float* out = (float*)d_out;

    char* ws = (char*)d_ws;
    unsigned short* whT2 = (unsigned short*)ws;                          // 4 MB
    float*    esrc  = (float*)(ws + (4u << 20));                         // 256 KB
    unsigned* ejP   = (unsigned*)(ws + (4u << 20) + (256u << 10));       // 256 KB
    unsigned* bitsG = (unsigned*)(ws + (4u << 20) + (512u << 10));       // 2 MB
    float*    we_g  = (float*)(ws + (4u << 20) + (512u << 10) + (2u << 20)); // 16 KB

    adjprep_kernel<<<dim3(2064), dim3(256), 0, stream>>>(adj, W, a, bitsG, we_g);
    prepw_kernel  <<<dim3(1024), dim3(256), 0, stream>>>(x, W, we_g, whT2, esrc, ejP);
    attn_kernel   <<<dim3(1024), dim3(256), 0, stream>>>(whT2, esrc, ejP, bitsG, out);
}